// Round 8
// baseline (659.800 us; speedup 1.0000x reference)
//
#include <hip/hip_runtime.h>

#define NN 100000
#define NE 1600000
#define NG 64
#define DI 128
#define DH 256
#define DO 128

using short8 = __attribute__((ext_vector_type(8))) short;
using f32x4  = __attribute__((ext_vector_type(4))) float;

__device__ __forceinline__ float bf2f(unsigned short u) {
    return __uint_as_float(((unsigned)u) << 16);
}
__device__ __forceinline__ unsigned short f2bf(float f) {
    unsigned u = __float_as_uint(f);
    unsigned r = (u + 0x7FFFu + ((u >> 16) & 1u)) >> 16;   // RNE
    return (unsigned short)r;
}

// ---------------- small utility kernels ----------------

__global__ void k_zero(float* p, int n) {
    int i = blockIdx.x * blockDim.x + threadIdx.x;
    if (i < n) p[i] = 0.0f;
}
__global__ void k_zero_int(int* p, int n) {
    int i = blockIdx.x * blockDim.x + threadIdx.x;
    if (i < n) p[i] = 0;
}
__global__ void k_hist(const int* __restrict__ dst, int* __restrict__ cnt, int e) {
    int i = blockIdx.x * blockDim.x + threadIdx.x;
    if (i < e) atomicAdd(&cnt[dst[i]], 1);
}

// f32 -> bf16 bulk convert
__global__ void k_cvt_bf(const float* __restrict__ in, unsigned short* __restrict__ out, int n4) {
    int i = blockIdx.x * blockDim.x + threadIdx.x;
    if (i >= n4) return;
    float4 v = ((const float4*)in)[i];
    ushort4 o;
    o.x = f2bf(v.x); o.y = f2bf(v.y); o.z = f2bf(v.z); o.w = f2bf(v.w);
    ((ushort4*)out)[i] = o;
}

// W (KxN f32, row-major) -> Wt (NxK bf16)
__global__ void k_wt(const float* __restrict__ W, unsigned short* __restrict__ Wt, int K, int N) {
    int i = blockIdx.x * blockDim.x + threadIdx.x;
    if (i >= K * N) return;
    int k = i / N, n = i % N;
    Wt[n * K + k] = f2bf(W[i]);
}

// ---------------- exclusive scan (2-level) ----------------

__global__ void k_scan1(const int* __restrict__ in, int* __restrict__ out,
                        int* __restrict__ bsum, int n) {
    __shared__ int sh[256];
    int t = threadIdx.x;
    int i = blockIdx.x * 256 + t;
    int v = (i < n) ? in[i] : 0;
    sh[t] = v;
    __syncthreads();
    for (int off = 1; off < 256; off <<= 1) {
        int add = (t >= off) ? sh[t - off] : 0;
        __syncthreads();
        sh[t] += add;
        __syncthreads();
    }
    if (i < n) out[i] = sh[t] - v;
    if (t == 255) bsum[blockIdx.x] = sh[255];
}
__global__ void k_scan2(int* __restrict__ bsum, int nb) {
    __shared__ int sh[512];
    int t = threadIdx.x;
    int v = (t < nb) ? bsum[t] : 0;
    sh[t] = v;
    __syncthreads();
    for (int off = 1; off < 512; off <<= 1) {
        int add = (t >= off) ? sh[t - off] : 0;
        __syncthreads();
        sh[t] += add;
        __syncthreads();
    }
    if (t < nb) bsum[t] = sh[t] - v;
}
// finalize rowst, init cursor, compute dinv
__global__ void k_scan3(int* __restrict__ rowst, const int* __restrict__ bsum,
                        int* __restrict__ cursor_deg, float* __restrict__ dinv,
                        int n, int total) {
    int i = blockIdx.x * 256 + threadIdx.x;
    if (i < n) {
        int deg = cursor_deg[i];
        dinv[i] = rsqrtf((float)(deg + 1));
        int rv = rowst[i] + bsum[blockIdx.x];
        rowst[i] = rv;
        cursor_deg[i] = rv;   // becomes fill cursor
    }
    if (i == 0) rowst[n] = total;
}

// ---------------- CSR fill: dst-range passes ----------------

__global__ void k_fill_csr(const int* __restrict__ src, const int* __restrict__ dst,
                           int* __restrict__ cursor, int* __restrict__ csr_src,
                           int e, int lo, int hi) {
    int i = blockIdx.x * blockDim.x + threadIdx.x;
    if (i < e) {
        int d = dst[i];
        if (d >= lo && d < hi) {
            int pos = atomicAdd(&cursor[d], 1);
            csr_src[pos] = src[i];
        }
    }
}

// ---------------- layer-1 aggregation: out = A_hat @ feat (bf16->bf16), D=128 ----------------
// 16 lanes per node, short8 (16B) per lane, 4-way neighbor unroll. (R5-proven)
__global__ __launch_bounds__(256) void k_agg16(const unsigned short* __restrict__ feat,
        const int* __restrict__ csr_src, const int* __restrict__ row_start,
        const float* __restrict__ dinv, unsigned short* __restrict__ out, int n) {
    int gid = blockIdx.x * blockDim.x + threadIdx.x;
    int node = gid >> 4;
    int lane = threadIdx.x & 15;
    if (node >= n) return;
    const short8* f8 = (const short8*)feat;
    float wd = dinv[node];
    short8 a = f8[(size_t)node * 16 + lane];
    float acc[8];
#pragma unroll
    for (int i = 0; i < 8; ++i) acc[i] = bf2f((unsigned short)a[i]) * wd;
    int j = row_start[node], end = row_start[node + 1];
    for (; j + 3 < end; j += 4) {
        int s0 = csr_src[j], s1 = csr_src[j + 1], s2 = csr_src[j + 2], s3 = csr_src[j + 3];
        float w0 = dinv[s0], w1 = dinv[s1], w2 = dinv[s2], w3 = dinv[s3];
        short8 v0 = f8[(size_t)s0 * 16 + lane];
        short8 v1 = f8[(size_t)s1 * 16 + lane];
        short8 v2 = f8[(size_t)s2 * 16 + lane];
        short8 v3 = f8[(size_t)s3 * 16 + lane];
#pragma unroll
        for (int i = 0; i < 8; ++i)
            acc[i] += w0 * bf2f((unsigned short)v0[i]) + w1 * bf2f((unsigned short)v1[i])
                    + w2 * bf2f((unsigned short)v2[i]) + w3 * bf2f((unsigned short)v3[i]);
    }
    for (; j < end; ++j) {
        int s = csr_src[j];
        float w = dinv[s];
        short8 v = f8[(size_t)s * 16 + lane];
#pragma unroll
        for (int i = 0; i < 8; ++i) acc[i] += w * bf2f((unsigned short)v[i]);
    }
    short8 o;
#pragma unroll
    for (int i = 0; i < 8; ++i) o[i] = (short)f2bf(acc[i] * wd);
    ((short8*)out)[(size_t)node * 16 + lane] = o;
}

// ---------------- coefficient matrix build: C[s][g] ----------------
// edge (s,d): C[s][batch[d]] += dinv_s * dinv_d
__global__ void k_cbuild(const int* __restrict__ src, const int* __restrict__ dst,
                         const int* __restrict__ batch, const float* __restrict__ dinv,
                         float* __restrict__ c, int e) {
    int i = blockIdx.x * blockDim.x + threadIdx.x;
    if (i < e) {
        int s = src[i], d = dst[i];
        float w = dinv[s] * dinv[d];
        atomicAdd(&c[(size_t)s * NG + batch[d]], w);
    }
}
// self-loop term: C[v][batch[v]] += dinv_v^2
__global__ void k_cself(const int* __restrict__ batch, const float* __restrict__ dinv,
                        float* __restrict__ c, int n) {
    int i = blockIdx.x * blockDim.x + threadIdx.x;
    if (i < n) {
        float w = dinv[i];
        atomicAdd(&c[(size_t)i * NG + batch[i]], w * w);
    }
}
// nodes-per-graph histogram (LDS-staged)
__global__ void k_cnth(const int* __restrict__ batch, int* __restrict__ cntg, int n) {
    __shared__ int sh[NG];
    int t = threadIdx.x;
    if (t < NG) sh[t] = 0;
    __syncthreads();
    int i = blockIdx.x * 256 + t;
    if (i < n) atomicAdd(&sh[batch[i]], 1);
    __syncthreads();
    if (t < NG && sh[t]) atomicAdd(&cntg[t], sh[t]);
}

// ---------------- pre = C^T @ h1  (64 x 256), partial per block ----------------
// 256 blocks x 512 threads; thread: col j = t&255, graph-half h = t>>8 (32 graphs).
__global__ __launch_bounds__(512) void k_cgemm(const unsigned short* __restrict__ h1,
        const float* __restrict__ c, float* __restrict__ partial, int n) {
    int t = threadIdx.x;
    int j = t & 255;
    int h = t >> 8;
    int b = blockIdx.x;
    const int chunk = (NN + 255) / 256;   // 391
    int s0 = b * chunk;
    int s1 = min(s0 + chunk, n);

    float acc[32];
#pragma unroll
    for (int g = 0; g < 32; ++g) acc[g] = 0.f;

    for (int s = s0; s < s1; ++s) {
        float tv = bf2f(h1[(size_t)s * DH + j]);
        const float4* c4 = (const float4*)(c + (size_t)s * NG + h * 32);
        float4 r0 = c4[0], r1 = c4[1], r2 = c4[2], r3 = c4[3];
        float4 r4 = c4[4], r5 = c4[5], r6 = c4[6], r7 = c4[7];
        acc[0]  = fmaf(r0.x, tv, acc[0]);  acc[1]  = fmaf(r0.y, tv, acc[1]);
        acc[2]  = fmaf(r0.z, tv, acc[2]);  acc[3]  = fmaf(r0.w, tv, acc[3]);
        acc[4]  = fmaf(r1.x, tv, acc[4]);  acc[5]  = fmaf(r1.y, tv, acc[5]);
        acc[6]  = fmaf(r1.z, tv, acc[6]);  acc[7]  = fmaf(r1.w, tv, acc[7]);
        acc[8]  = fmaf(r2.x, tv, acc[8]);  acc[9]  = fmaf(r2.y, tv, acc[9]);
        acc[10] = fmaf(r2.z, tv, acc[10]); acc[11] = fmaf(r2.w, tv, acc[11]);
        acc[12] = fmaf(r3.x, tv, acc[12]); acc[13] = fmaf(r3.y, tv, acc[13]);
        acc[14] = fmaf(r3.z, tv, acc[14]); acc[15] = fmaf(r3.w, tv, acc[15]);
        acc[16] = fmaf(r4.x, tv, acc[16]); acc[17] = fmaf(r4.y, tv, acc[17]);
        acc[18] = fmaf(r4.z, tv, acc[18]); acc[19] = fmaf(r4.w, tv, acc[19]);
        acc[20] = fmaf(r5.x, tv, acc[20]); acc[21] = fmaf(r5.y, tv, acc[21]);
        acc[22] = fmaf(r5.z, tv, acc[22]); acc[23] = fmaf(r5.w, tv, acc[23]);
        acc[24] = fmaf(r6.x, tv, acc[24]); acc[25] = fmaf(r6.y, tv, acc[25]);
        acc[26] = fmaf(r6.z, tv, acc[26]); acc[27] = fmaf(r6.w, tv, acc[27]);
        acc[28] = fmaf(r7.x, tv, acc[28]); acc[29] = fmaf(r7.y, tv, acc[29]);
        acc[30] = fmaf(r7.z, tv, acc[30]); acc[31] = fmaf(r7.w, tv, acc[31]);
    }

    float* pb = partial + (size_t)b * (NG * DH);
#pragma unroll
    for (int g = 0; g < 32; ++g)
        pb[(h * 32 + g) * DH + j] = acc[g];
}

// reduce partials: pre[idx] = sum_b partial[b][idx], idx < 64*256
__global__ void k_reduce(const float* __restrict__ partial, float* __restrict__ pre) {
    int idx = blockIdx.x * 256 + threadIdx.x;
    if (idx >= NG * DH) return;
    float s0 = 0.f, s1 = 0.f, s2 = 0.f, s3 = 0.f;
    for (int b = 0; b < 256; b += 4) {
        s0 += partial[(size_t)b * (NG * DH) + idx];
        s1 += partial[(size_t)(b + 1) * (NG * DH) + idx];
        s2 += partial[(size_t)(b + 2) * (NG * DH) + idx];
        s3 += partial[(size_t)(b + 3) * (NG * DH) + idx];
    }
    pre[idx] = (s0 + s1) + (s2 + s3);
}

// out[g][j] = sum_k pre[g][k] * W2[k][j] + cnt[g] * b2[j]
__global__ void k_fgemm(const float* __restrict__ pre, const float* __restrict__ W2,
                        const float* __restrict__ b2, const int* __restrict__ cntg,
                        float* __restrict__ out) {
    int idx = blockIdx.x * 256 + threadIdx.x;
    if (idx >= NG * DO) return;
    int g = idx >> 7, j = idx & 127;
    float acc = (float)cntg[g] * b2[j];
    const float* pr = pre + g * DH;
    for (int k = 0; k < DH; ++k)
        acc = fmaf(pr[k], W2[k * DO + j], acc);
    out[idx] = acc;
}

// ---------------- bf16 MFMA GEMM: C = act(A @ Bt^T + bias), BM=128, 512 thr ----------------
template<int K, int N, bool RELU, bool BIAS>
__global__ __launch_bounds__(512) void k_gemm_bf(const unsigned short* __restrict__ A,
        const unsigned short* __restrict__ Bt, const float* __restrict__ bias,
        unsigned short* __restrict__ C, int M) {
    constexpr int BM = 128;
    __shared__ unsigned short As[BM * K];   // XOR-swizzled rows
    __shared__ unsigned short Bs[N * K];

    const int tid = threadIdx.x;
    const int bm = blockIdx.x * BM;

    constexpr int AC = BM * K / 8;
    for (int c = tid; c < AC; c += 512) {
        int row = c / (K / 8);
        int kc  = (c % (K / 8)) * 8;
        uint4 v = make_uint4(0, 0, 0, 0);
        int gr = bm + row;
        if (gr < M) v = *(const uint4*)(A + (size_t)gr * K + kc);
        int byte = row * (2 * K) + ((kc * 2) ^ ((row & 7) << 4));
        *(uint4*)((char*)As + byte) = v;
    }
    constexpr int BC = N * K / 8;
    for (int c = tid; c < BC; c += 512) {
        int col = c / (K / 8);
        int kc  = (c % (K / 8)) * 8;
        uint4 v = *(const uint4*)(Bt + (size_t)col * K + kc);
        int byte = col * (2 * K) + ((kc * 2) ^ ((col & 7) << 4));
        *(uint4*)((char*)Bs + byte) = v;
    }
    __syncthreads();

    const int w  = tid >> 6;
    const int l  = tid & 63;
    const int lr = l & 15;
    const int lg = l >> 4;
    const int r0 = w * 16;

    constexpr int NT = N / 16;
    f32x4 acc[NT] = {};

    const int arow  = r0 + lr;
    const int abase = arow * (2 * K);
    const int aswz  = (arow & 7) << 4;

#pragma unroll
    for (int ks = 0; ks < K / 32; ++ks) {
        int kb = ks * 64 + lg * 16;
        short8 a = *(const short8*)((const char*)As + abase + (kb ^ aswz));
#pragma unroll
        for (int n = 0; n < NT; ++n) {
            int col = n * 16 + lr;
            short8 b = *(const short8*)((const char*)Bs + col * (2 * K) + (kb ^ ((col & 7) << 4)));
            acc[n] = __builtin_amdgcn_mfma_f32_16x16x32_bf16(a, b, acc[n], 0, 0, 0);
        }
    }

#pragma unroll
    for (int n = 0; n < NT; ++n) {
        int col = n * 16 + lr;
        float bb = BIAS ? bias[col] : 0.0f;
#pragma unroll
        for (int r = 0; r < 4; ++r) {
            int row = bm + r0 + lg * 4 + r;
            if (row < M) {
                float v = acc[n][r] + bb;
                if (RELU) v = fmaxf(v, 0.f);
                C[(size_t)row * N + col] = f2bf(v);
            }
        }
    }
}

// ---------------- launch ----------------

extern "C" void kernel_launch(void* const* d_in, const int* in_sizes, int n_in,
                              void* d_out, int out_size, void* d_ws, size_t ws_size,
                              hipStream_t stream) {
    const float* x     = (const float*)d_in[0];
    const int*   ei    = (const int*)d_in[1];
    const int*   batch = (const int*)d_in[2];
    const float* W1    = (const float*)d_in[3];
    const float* b1    = (const float*)d_in[4];
    const float* W2    = (const float*)d_in[5];
    const float* b2    = (const float*)d_in[6];
    float* out = (float*)d_out;

    const int* src = ei;
    const int* dst = ei + NE;

    // workspace layout (16B aligned), ~153.2 MB total
    char* ws = (char*)d_ws;
    float*          dinv    = (float*)(ws + 0);                 // 400 KB
    int*            cnt_in  = (int*)(ws + 524288);              // 400 KB (deg -> cursor)
    int*            rowst   = (int*)(ws + 1048576);             // NN+1 ints
    int*            bsum    = (int*)(ws + 1572864);             // 2 KB
    int*            cntg    = (int*)(ws + 1576960);             // 256 B
    unsigned short* w1t     = (unsigned short*)(ws + 1581056);  // 64 KB
    int*            csr     = (int*)(ws + 1712128);             // 6.4 MB
    unsigned short* xbf     = (unsigned short*)(ws + 8388608);  // 25.6 MB
    unsigned short* agg1    = (unsigned short*)(ws + 33988608); // 25.6 MB
    unsigned short* h1      = (unsigned short*)(ws + 59588608); // 51.2 MB
    float*          cmat    = (float*)(ws + 110788608);         // 25.6 MB
    float*          partial = (float*)(ws + 136388608);         // 16.78 MB
    float*          pre     = (float*)(ws + 153165824);         // 64 KB

    const int BLK = 256;
    auto cdiv = [](int a, int b) { return (a + b - 1) / b; };
    const int NB = cdiv(NN, 256);   // 391

    // ---- conversions ----
    k_cvt_bf<<<cdiv(NN * 32, BLK), BLK, 0, stream>>>(x, xbf, NN * 32);
    k_wt<<<cdiv(DI * DH, BLK), BLK, 0, stream>>>(W1, w1t, DI, DH);

    // ---- degree + CSR build ----
    k_zero_int<<<cdiv(NN, BLK), BLK, 0, stream>>>(cnt_in, NN);
    k_hist<<<cdiv(NE, BLK), BLK, 0, stream>>>(dst, cnt_in, NE);
    k_scan1<<<NB, 256, 0, stream>>>(cnt_in, rowst, bsum, NN);
    k_scan2<<<1, 512, 0, stream>>>(bsum, NB);
    k_scan3<<<NB, 256, 0, stream>>>(rowst, bsum, cnt_in, dinv, NN, NE);
    {
        const int NPASS = 4, NPP = (NN + NPASS - 1) / NPASS;
        for (int p = 0; p < NPASS; ++p)
            k_fill_csr<<<cdiv(NE, BLK), BLK, 0, stream>>>(src, dst, cnt_in, csr, NE,
                                                          p * NPP, (p + 1) * NPP);
    }

    // ---- pool-coefficient matrix C (NN x 64) + graph node counts ----
    k_zero<<<cdiv(NN * NG, BLK), BLK, 0, stream>>>(cmat, NN * NG);
    k_cbuild<<<cdiv(NE, BLK), BLK, 0, stream>>>(src, dst, batch, dinv, cmat, NE);
    k_cself<<<cdiv(NN, BLK), BLK, 0, stream>>>(batch, dinv, cmat, NN);
    k_zero_int<<<1, 64, 0, stream>>>(cntg, NG);
    k_cnth<<<NB, 256, 0, stream>>>(batch, cntg, NN);

    // ---- layer 1: agg1 = A_hat @ x ; h1 = relu(agg1 @ W1 + b1) ----
    k_agg16<<<cdiv(NN * 16, BLK), BLK, 0, stream>>>(xbf, csr, rowst, dinv, agg1, NN);
    k_gemm_bf<DI, DH, true, true><<<cdiv(NN, 128), 512, 0, stream>>>(agg1, w1t, b1, h1, NN);

    // ---- layer 2 tail: out = (C^T h1) W2 + cnt*b2 ----
    k_cgemm<<<256, 512, 0, stream>>>(h1, cmat, partial, NN);
    k_reduce<<<cdiv(NG * DH, 256), 256, 0, stream>>>(partial, pre);
    k_fgemm<<<cdiv(NG * DO, 256), 256, 0, stream>>>(pre, W2, b2, cntg, out);
}

// Round 9
// 417.407 us; speedup vs baseline: 1.5807x; 1.5807x over previous
//
#include <hip/hip_runtime.h>

#define NN 100000
#define NNPAD 100352   // 196*512 = 784*128
#define NE 1600000
#define NG 64
#define DI 128
#define DH 256
#define DO 128

using short8 = __attribute__((ext_vector_type(8))) short;
using f32x4  = __attribute__((ext_vector_type(4))) float;

__device__ __forceinline__ float bf2f(unsigned short u) {
    return __uint_as_float(((unsigned)u) << 16);
}
__device__ __forceinline__ unsigned short f2bf(float f) {
    unsigned u = __float_as_uint(f);
    unsigned r = (u + 0x7FFFu + ((u >> 16) & 1u)) >> 16;   // RNE
    return (unsigned short)r;
}

// ---------------- small utility kernels ----------------

__global__ void k_zero(float* p, int n) {
    int i = blockIdx.x * blockDim.x + threadIdx.x;
    if (i < n) p[i] = 0.0f;
}
__global__ void k_zero_int(int* p, int n) {
    int i = blockIdx.x * blockDim.x + threadIdx.x;
    if (i < n) p[i] = 0;
}
__global__ void k_hist(const int* __restrict__ dst, int* __restrict__ cnt, int e) {
    int i = blockIdx.x * blockDim.x + threadIdx.x;
    if (i < e) atomicAdd(&cnt[dst[i]], 1);
}

// f32 -> bf16 bulk convert (4 elems/thread)
__global__ void k_cvt_bf(const float* __restrict__ in, unsigned short* __restrict__ out, int n4) {
    int i = blockIdx.x * blockDim.x + threadIdx.x;
    if (i >= n4) return;
    float4 v = ((const float4*)in)[i];
    ushort4 o;
    o.x = f2bf(v.x); o.y = f2bf(v.y); o.z = f2bf(v.z); o.w = f2bf(v.w);
    ((ushort4*)out)[i] = o;
}

// W (KxN f32, row-major) -> Wt (NxK bf16)
__global__ void k_wt(const float* __restrict__ W, unsigned short* __restrict__ Wt, int K, int N) {
    int i = blockIdx.x * blockDim.x + threadIdx.x;
    if (i >= K * N) return;
    int k = i / N, n = i % N;
    Wt[n * K + k] = f2bf(W[i]);
}

// ---------------- exclusive scan (2-level) ----------------

__global__ void k_scan1(const int* __restrict__ in, int* __restrict__ out,
                        int* __restrict__ bsum, int n) {
    __shared__ int sh[256];
    int t = threadIdx.x;
    int i = blockIdx.x * 256 + t;
    int v = (i < n) ? in[i] : 0;
    sh[t] = v;
    __syncthreads();
    for (int off = 1; off < 256; off <<= 1) {
        int add = (t >= off) ? sh[t - off] : 0;
        __syncthreads();
        sh[t] += add;
        __syncthreads();
    }
    if (i < n) out[i] = sh[t] - v;
    if (t == 255) bsum[blockIdx.x] = sh[255];
}
__global__ void k_scan2(int* __restrict__ bsum, int nb) {
    __shared__ int sh[512];
    int t = threadIdx.x;
    int v = (t < nb) ? bsum[t] : 0;
    sh[t] = v;
    __syncthreads();
    for (int off = 1; off < 512; off <<= 1) {
        int add = (t >= off) ? sh[t - off] : 0;
        __syncthreads();
        sh[t] += add;
        __syncthreads();
    }
    if (t < nb) bsum[t] = sh[t] - v;
}
// finalize rowst, init cursor, compute dinv
__global__ void k_scan3(int* __restrict__ rowst, const int* __restrict__ bsum,
                        int* __restrict__ cursor_deg, float* __restrict__ dinv,
                        int n, int total) {
    int i = blockIdx.x * 256 + threadIdx.x;
    if (i < n) {
        int deg = cursor_deg[i];
        dinv[i] = rsqrtf((float)(deg + 1));
        int rv = rowst[i] + bsum[blockIdx.x];
        rowst[i] = rv;
        cursor_deg[i] = rv;   // becomes fill cursor
    }
    if (i == 0) rowst[n] = total;
}

// ---------------- CSR fill: dst-range passes ----------------

__global__ void k_fill_csr(const int* __restrict__ src, const int* __restrict__ dst,
                           int* __restrict__ cursor, int* __restrict__ csr_src,
                           int e, int lo, int hi) {
    int i = blockIdx.x * blockDim.x + threadIdx.x;
    if (i < e) {
        int d = dst[i];
        if (d >= lo && d < hi) {
            int pos = atomicAdd(&cursor[d], 1);
            csr_src[pos] = src[i];
        }
    }
}

// ---------------- layer-1 aggregation (R5-proven) ----------------
__global__ __launch_bounds__(256) void k_agg16(const unsigned short* __restrict__ feat,
        const int* __restrict__ csr_src, const int* __restrict__ row_start,
        const float* __restrict__ dinv, unsigned short* __restrict__ out, int n) {
    int gid = blockIdx.x * blockDim.x + threadIdx.x;
    int node = gid >> 4;
    int lane = threadIdx.x & 15;
    if (node >= n) return;
    const short8* f8 = (const short8*)feat;
    float wd = dinv[node];
    short8 a = f8[(size_t)node * 16 + lane];
    float acc[8];
#pragma unroll
    for (int i = 0; i < 8; ++i) acc[i] = bf2f((unsigned short)a[i]) * wd;
    int j = row_start[node], end = row_start[node + 1];
    for (; j + 3 < end; j += 4) {
        int s0 = csr_src[j], s1 = csr_src[j + 1], s2 = csr_src[j + 2], s3 = csr_src[j + 3];
        float w0 = dinv[s0], w1 = dinv[s1], w2 = dinv[s2], w3 = dinv[s3];
        short8 v0 = f8[(size_t)s0 * 16 + lane];
        short8 v1 = f8[(size_t)s1 * 16 + lane];
        short8 v2 = f8[(size_t)s2 * 16 + lane];
        short8 v3 = f8[(size_t)s3 * 16 + lane];
#pragma unroll
        for (int i = 0; i < 8; ++i)
            acc[i] += w0 * bf2f((unsigned short)v0[i]) + w1 * bf2f((unsigned short)v1[i])
                    + w2 * bf2f((unsigned short)v2[i]) + w3 * bf2f((unsigned short)v3[i]);
    }
    for (; j < end; ++j) {
        int s = csr_src[j];
        float w = dinv[s];
        short8 v = f8[(size_t)s * 16 + lane];
#pragma unroll
        for (int i = 0; i < 8; ++i) acc[i] += w * bf2f((unsigned short)v[i]);
    }
    short8 o;
#pragma unroll
    for (int i = 0; i < 8; ++i) o[i] = (short)f2bf(acc[i] * wd);
    ((short8*)out)[(size_t)node * 16 + lane] = o;
}

// ---------------- transposed coefficient matrix: cmT[g][s] ----------------
__global__ void k_cbuildT(const int* __restrict__ src, const int* __restrict__ dst,
                          const int* __restrict__ batch, const float* __restrict__ dinv,
                          float* __restrict__ cmT, int e) {
    int i = blockIdx.x * blockDim.x + threadIdx.x;
    if (i < e) {
        int s = src[i], d = dst[i];
        atomicAdd(&cmT[(size_t)batch[d] * NNPAD + s], dinv[s] * dinv[d]);
    }
}
__global__ void k_cselfT(const int* __restrict__ batch, const float* __restrict__ dinv,
                         float* __restrict__ cmT, int n) {
    int i = blockIdx.x * blockDim.x + threadIdx.x;
    if (i < n) {
        float w = dinv[i];
        atomicAdd(&cmT[(size_t)batch[i] * NNPAD + i], w * w);
    }
}
__global__ void k_cnth(const int* __restrict__ batch, int* __restrict__ cntg, int n) {
    __shared__ int sh[NG];
    int t = threadIdx.x;
    if (t < NG) sh[t] = 0;
    __syncthreads();
    int i = blockIdx.x * 256 + t;
    if (i < n) atomicAdd(&sh[batch[i]], 1);
    __syncthreads();
    if (t < NG && sh[t]) atomicAdd(&cntg[t], sh[t]);
}

// ---------------- gemm_t: h1T = relu(W1^T @ agg1^T + b1), output 256 x NNPAD ----------------
// A = w1t (256x128 bf16), Bt = agg1 (node-major, K=128 contiguous). BN=128 nodes/block.
__global__ __launch_bounds__(512) void k_gemm_t(const unsigned short* __restrict__ w1t,
        const unsigned short* __restrict__ agg1, const float* __restrict__ b1,
        unsigned short* __restrict__ h1T) {
    __shared__ unsigned short As[256 * 128];   // 64 KB, XOR-swizzled rows (256B each)
    __shared__ unsigned short Bs[128 * 128];   // 32 KB

    const int tid = threadIdx.x;
    const int bn = blockIdx.x * 128;

    // stage A: 4096 x 16B chunks
#pragma unroll
    for (int i = 0; i < 8; ++i) {
        int c = tid + i * 512;
        int row = c >> 4, seg = c & 15;
        uint4 v = *(const uint4*)(w1t + row * 128 + seg * 8);
        *(uint4*)((char*)As + row * 256 + ((seg * 16) ^ ((row & 7) << 4))) = v;
    }
    // stage B: 2048 x 16B chunks (guard node < NN)
#pragma unroll
    for (int i = 0; i < 4; ++i) {
        int c = tid + i * 512;
        int row = c >> 4, seg = c & 15;
        uint4 v = make_uint4(0, 0, 0, 0);
        if (bn + row < NN) v = *(const uint4*)(agg1 + (size_t)(bn + row) * 128 + seg * 8);
        *(uint4*)((char*)Bs + row * 256 + ((seg * 16) ^ ((row & 7) << 4))) = v;
    }
    __syncthreads();

    const int w  = tid >> 6;
    const int l  = tid & 63;
    const int lr = l & 15;
    const int lg = l >> 4;
    const int m0 = w * 32;
    const int swz = (lr & 7) << 4;

    f32x4 acc[2][8] = {};

#pragma unroll
    for (int ks = 0; ks < 4; ++ks) {
        int kb = ks * 64 + lg * 16;
        short8 a0 = *(const short8*)((const char*)As + (m0 + lr) * 256 + (kb ^ swz));
        short8 a1 = *(const short8*)((const char*)As + (m0 + 16 + lr) * 256 + (kb ^ swz));
#pragma unroll
        for (int nt = 0; nt < 8; ++nt) {
            short8 b = *(const short8*)((const char*)Bs + (nt * 16 + lr) * 256 + (kb ^ swz));
            acc[0][nt] = __builtin_amdgcn_mfma_f32_16x16x32_bf16(a0, b, acc[0][nt], 0, 0, 0);
            acc[1][nt] = __builtin_amdgcn_mfma_f32_16x16x32_bf16(a1, b, acc[1][nt], 0, 0, 0);
        }
    }

#pragma unroll
    for (int mi = 0; mi < 2; ++mi) {
#pragma unroll
        for (int nt = 0; nt < 8; ++nt) {
#pragma unroll
            for (int r = 0; r < 4; ++r) {
                int j = m0 + mi * 16 + lg * 4 + r;     // hidden index
                int s = bn + nt * 16 + lr;             // node index
                float v = fmaxf(acc[mi][nt][r] + b1[j], 0.0f);
                h1T[(size_t)j * NNPAD + s] = (s < NN) ? f2bf(v) : (unsigned short)0;
            }
        }
    }
}

// ---------------- cgemm2: partial[b] = cmTb[:, sb:sb+512] @ h1T[:, sb:sb+512]^T ----------------
// out tile 64 x 256 per block, split-K over 196 blocks.
__global__ __launch_bounds__(512) void k_cgemm2(const unsigned short* __restrict__ cmTb,
        const unsigned short* __restrict__ h1T, float* __restrict__ partial) {
    __shared__ unsigned short As[64 * 64];    // 8 KB  (g rows, 128B each)
    __shared__ unsigned short Bs[256 * 64];   // 32 KB (j rows, 128B each)

    const int tid = threadIdx.x;
    const int sb = blockIdx.x * 512;

    const int w  = tid >> 6;
    const int l  = tid & 63;
    const int lr = l & 15;
    const int lg = l >> 4;
    const int swz = (lr & 7) << 4;

    f32x4 acc[4][2] = {};

    for (int kc = 0; kc < 8; ++kc) {
        int s0 = sb + kc * 64;
        __syncthreads();
        {   // stage A: 512 x 16B
            int g = tid >> 3, seg = tid & 7;
            uint4 v = *(const uint4*)(cmTb + (size_t)g * NNPAD + s0 + seg * 8);
            *(uint4*)((char*)As + g * 128 + ((seg * 16) ^ ((g & 7) << 4))) = v;
        }
#pragma unroll
        for (int i = 0; i < 4; ++i) {   // stage B: 2048 x 16B
            int c = tid + i * 512;
            int j = c >> 3, seg = c & 7;
            uint4 v = *(const uint4*)(h1T + (size_t)j * NNPAD + s0 + seg * 8);
            *(uint4*)((char*)Bs + j * 128 + ((seg * 16) ^ ((j & 7) << 4))) = v;
        }
        __syncthreads();

#pragma unroll
        for (int kk = 0; kk < 2; ++kk) {
            int kb = kk * 64 + lg * 16;
            short8 a[4];
#pragma unroll
            for (int mi = 0; mi < 4; ++mi)
                a[mi] = *(const short8*)((const char*)As + (mi * 16 + lr) * 128 + (kb ^ swz));
#pragma unroll
            for (int ntl = 0; ntl < 2; ++ntl) {
                int j = (w * 2 + ntl) * 16 + lr;
                short8 b = *(const short8*)((const char*)Bs + j * 128 + (kb ^ swz));
#pragma unroll
                for (int mi = 0; mi < 4; ++mi)
                    acc[mi][ntl] = __builtin_amdgcn_mfma_f32_16x16x32_bf16(a[mi], b, acc[mi][ntl], 0, 0, 0);
            }
        }
    }

    float* pb = partial + (size_t)blockIdx.x * (NG * DH);
#pragma unroll
    for (int mi = 0; mi < 4; ++mi)
#pragma unroll
        for (int ntl = 0; ntl < 2; ++ntl)
#pragma unroll
            for (int r = 0; r < 4; ++r) {
                int g = mi * 16 + lg * 4 + r;
                int j = (w * 2 + ntl) * 16 + lr;
                pb[g * DH + j] = acc[mi][ntl][r];
            }
}

// reduce partials over 196 blocks
__global__ void k_reduce196(const float* __restrict__ partial, float* __restrict__ pre) {
    int idx = blockIdx.x * 256 + threadIdx.x;
    if (idx >= NG * DH) return;
    float s0 = 0.f, s1 = 0.f, s2 = 0.f, s3 = 0.f;
    for (int b = 0; b < 196; b += 4) {
        s0 += partial[(size_t)b * (NG * DH) + idx];
        s1 += partial[(size_t)(b + 1) * (NG * DH) + idx];
        s2 += partial[(size_t)(b + 2) * (NG * DH) + idx];
        s3 += partial[(size_t)(b + 3) * (NG * DH) + idx];
    }
    pre[idx] = (s0 + s1) + (s2 + s3);
}

// out[g][j] = sum_k pre[g][k] * W2[k][j] + cnt[g]*b2[j]
__global__ void k_fgemm(const float* __restrict__ pre, const float* __restrict__ W2,
                        const float* __restrict__ b2, const int* __restrict__ cntg,
                        float* __restrict__ out) {
    int idx = blockIdx.x * 256 + threadIdx.x;
    if (idx >= NG * DO) return;
    int g = idx >> 7, j = idx & 127;
    float acc = (float)cntg[g] * b2[j];
    const float* pr = pre + g * DH;
    for (int k = 0; k < DH; ++k)
        acc = fmaf(pr[k], W2[k * DO + j], acc);
    out[idx] = acc;
}

// ---------------- launch ----------------

extern "C" void kernel_launch(void* const* d_in, const int* in_sizes, int n_in,
                              void* d_out, int out_size, void* d_ws, size_t ws_size,
                              hipStream_t stream) {
    const float* x     = (const float*)d_in[0];
    const int*   ei    = (const int*)d_in[1];
    const int*   batch = (const int*)d_in[2];
    const float* W1    = (const float*)d_in[3];
    const float* b1    = (const float*)d_in[4];
    const float* W2    = (const float*)d_in[5];
    const float* b2    = (const float*)d_in[6];
    float* out = (float*)d_out;

    const int* src = ei;
    const int* dst = ei + NE;

    // workspace layout (phase-overlapped), peak ~124 MB
    char* ws = (char*)d_ws;
    float*          dinv    = (float*)(ws + 0);                  // 400 KB
    int*            cnt_in  = (int*)(ws + 524288);               // deg -> cursor
    int*            rowst   = (int*)(ws + 1048576);              // NN+1
    int*            bsum    = (int*)(ws + 1572864);
    int*            cntg    = (int*)(ws + 1576960);
    unsigned short* w1t     = (unsigned short*)(ws + 1581056);   // 64 KB
    int*            csr     = (int*)(ws + 1712128);              // 6.4 MB
    unsigned short* xbf     = (unsigned short*)(ws + 8388608);   // 25.6 MB  [phase 1]
    unsigned short* cmTb    = (unsigned short*)(ws + 8388608);   // 12.85 MB [phase 2, after agg16]
    unsigned short* agg1    = (unsigned short*)(ws + 33988608);  // 25.6 MB
    unsigned short* h1T     = (unsigned short*)(ws + 59588608);  // 51.38 MB (256 x NNPAD)
    float*          cmT     = (float*)(ws + 110968832);          // 25.69 MB [dead after cvt]
    float*          partial = (float*)(ws + 110968832);          // 12.85 MB [after cmT dead]
    float*          pre     = (float*)(ws + 123813888);          // 64 KB

    const int BLK = 256;
    auto cdiv = [](int a, int b) { return (a + b - 1) / b; };
    const int NB = cdiv(NN, 256);   // 391

    // ---- conversions ----
    k_cvt_bf<<<cdiv(NN * 32, BLK), BLK, 0, stream>>>(x, xbf, NN * 32);
    k_wt<<<cdiv(DI * DH, BLK), BLK, 0, stream>>>(W1, w1t, DI, DH);

    // ---- degree + CSR build ----
    k_zero_int<<<cdiv(NN, BLK), BLK, 0, stream>>>(cnt_in, NN);
    k_hist<<<cdiv(NE, BLK), BLK, 0, stream>>>(dst, cnt_in, NE);
    k_scan1<<<NB, 256, 0, stream>>>(cnt_in, rowst, bsum, NN);
    k_scan2<<<1, 512, 0, stream>>>(bsum, NB);
    k_scan3<<<NB, 256, 0, stream>>>(rowst, bsum, cnt_in, dinv, NN, NE);
    {
        const int NPASS = 4, NPP = (NN + NPASS - 1) / NPASS;
        for (int p = 0; p < NPASS; ++p)
            k_fill_csr<<<cdiv(NE, BLK), BLK, 0, stream>>>(src, dst, cnt_in, csr, NE,
                                                          p * NPP, (p + 1) * NPP);
    }

    // ---- transposed pool-coefficient matrix cmT (64 x NNPAD) + graph counts ----
    k_zero<<<cdiv(NG * NNPAD, BLK), BLK, 0, stream>>>(cmT, NG * NNPAD);
    k_cbuildT<<<cdiv(NE, BLK), BLK, 0, stream>>>(src, dst, batch, dinv, cmT, NE);
    k_cselfT<<<cdiv(NN, BLK), BLK, 0, stream>>>(batch, dinv, cmT, NN);
    k_zero_int<<<1, 64, 0, stream>>>(cntg, NG);
    k_cnth<<<NB, 256, 0, stream>>>(batch, cntg, NN);

    // ---- layer 1: agg1 = A_hat @ x ----
    k_agg16<<<cdiv(NN * 16, BLK), BLK, 0, stream>>>(xbf, csr, rowst, dinv, agg1, NN);

    // cmT -> bf16 (xbf now dead; cmTb overlays it)
    k_cvt_bf<<<cdiv(NG * NNPAD / 4, BLK), BLK, 0, stream>>>(cmT, cmTb, NG * NNPAD / 4);

    // h1T = relu(W1^T agg1^T + b1), 256 x NNPAD
    k_gemm_t<<<NNPAD / 128, 512, 0, stream>>>(w1t, agg1, b1, h1T);

    // ---- tail: pre = cmTb @ h1T^T ; out = pre W2 + cnt b2 ----
    k_cgemm2<<<NNPAD / 512, 512, 0, stream>>>(cmTb, h1T, partial);
    k_reduce196<<<cdiv(NG * DH, 256), 256, 0, stream>>>(partial, pre);
    k_fgemm<<<cdiv(NG * DO, 256), 256, 0, stream>>>(pre, W2, b2, cntg, out);
}

// Round 10
// 400.165 us; speedup vs baseline: 1.6488x; 1.0431x over previous
//
#include <hip/hip_runtime.h>

#define NN 100000
#define NNPAD 100352   // 196*512 = 784*128
#define NE 1600000
#define NG 64
#define DI 128
#define DH 256
#define DO 128

using short8 = __attribute__((ext_vector_type(8))) short;
using f32x4  = __attribute__((ext_vector_type(4))) float;

__device__ __forceinline__ float bf2f(unsigned short u) {
    return __uint_as_float(((unsigned)u) << 16);
}
__device__ __forceinline__ unsigned short f2bf(float f) {
    unsigned u = __float_as_uint(f);
    unsigned r = (u + 0x7FFFu + ((u >> 16) & 1u)) >> 16;   // RNE
    return (unsigned short)r;
}

// ---------------- small utility kernels ----------------

__global__ void k_zero_int(int* p, int n) {
    int i = blockIdx.x * blockDim.x + threadIdx.x;
    if (i < n) p[i] = 0;
}
__global__ void k_hist(const int* __restrict__ dst, int* __restrict__ cnt, int e) {
    int i = blockIdx.x * blockDim.x + threadIdx.x;
    if (i < e) atomicAdd(&cnt[dst[i]], 1);
}

// f32 -> bf16 bulk convert (4 elems/thread)
__global__ void k_cvt_bf(const float* __restrict__ in, unsigned short* __restrict__ out, int n4) {
    int i = blockIdx.x * blockDim.x + threadIdx.x;
    if (i >= n4) return;
    float4 v = ((const float4*)in)[i];
    ushort4 o;
    o.x = f2bf(v.x); o.y = f2bf(v.y); o.z = f2bf(v.z); o.w = f2bf(v.w);
    ((ushort4*)out)[i] = o;
}

// W (KxN f32, row-major) -> Wt (NxK bf16)
__global__ void k_wt(const float* __restrict__ W, unsigned short* __restrict__ Wt, int K, int N) {
    int i = blockIdx.x * blockDim.x + threadIdx.x;
    if (i >= K * N) return;
    int k = i / N, n = i % N;
    Wt[n * K + k] = f2bf(W[i]);
}

// ---------------- exclusive scan (2-level) ----------------

__global__ void k_scan1(const int* __restrict__ in, int* __restrict__ out,
                        int* __restrict__ bsum, int n) {
    __shared__ int sh[256];
    int t = threadIdx.x;
    int i = blockIdx.x * 256 + t;
    int v = (i < n) ? in[i] : 0;
    sh[t] = v;
    __syncthreads();
    for (int off = 1; off < 256; off <<= 1) {
        int add = (t >= off) ? sh[t - off] : 0;
        __syncthreads();
        sh[t] += add;
        __syncthreads();
    }
    if (i < n) out[i] = sh[t] - v;
    if (t == 255) bsum[blockIdx.x] = sh[255];
}
__global__ void k_scan2(int* __restrict__ bsum, int nb) {
    __shared__ int sh[512];
    int t = threadIdx.x;
    int v = (t < nb) ? bsum[t] : 0;
    sh[t] = v;
    __syncthreads();
    for (int off = 1; off < 512; off <<= 1) {
        int add = (t >= off) ? sh[t - off] : 0;
        __syncthreads();
        sh[t] += add;
        __syncthreads();
    }
    if (t < nb) bsum[t] = sh[t] - v;
}
// finalize rowst, init cursor, compute dinv, build packed (dinv,batch) table
__global__ void k_scan3(int* __restrict__ rowst, const int* __restrict__ bsum,
                        int* __restrict__ cursor_deg, float* __restrict__ dinv,
                        const int* __restrict__ batch, int2* __restrict__ gdv,
                        int n, int total) {
    int i = blockIdx.x * 256 + threadIdx.x;
    if (i < n) {
        int deg = cursor_deg[i];
        float dv = rsqrtf((float)(deg + 1));
        dinv[i] = dv;
        int2 g; g.x = __float_as_int(dv); g.y = batch[i];
        gdv[i] = g;
        int rv = rowst[i] + bsum[blockIdx.x];
        rowst[i] = rv;
        cursor_deg[i] = rv;   // becomes fill cursor
    }
    if (i == 0) rowst[n] = total;
}

// ---------------- CSR fill: dst-range passes ----------------

__global__ void k_fill_csr(const int* __restrict__ src, const int* __restrict__ dst,
                           int* __restrict__ cursor, int* __restrict__ csr_src,
                           int e, int lo, int hi) {
    int i = blockIdx.x * blockDim.x + threadIdx.x;
    if (i < e) {
        int d = dst[i];
        if (d >= lo && d < hi) {
            int pos = atomicAdd(&cursor[d], 1);
            csr_src[pos] = src[i];
        }
    }
}

// ---------------- layer-1 aggregation (R5-proven) ----------------
__global__ __launch_bounds__(256) void k_agg16(const unsigned short* __restrict__ feat,
        const int* __restrict__ csr_src, const int* __restrict__ row_start,
        const float* __restrict__ dinv, unsigned short* __restrict__ out, int n) {
    int gid = blockIdx.x * blockDim.x + threadIdx.x;
    int node = gid >> 4;
    int lane = threadIdx.x & 15;
    if (node >= n) return;
    const short8* f8 = (const short8*)feat;
    float wd = dinv[node];
    short8 a = f8[(size_t)node * 16 + lane];
    float acc[8];
#pragma unroll
    for (int i = 0; i < 8; ++i) acc[i] = bf2f((unsigned short)a[i]) * wd;
    int j = row_start[node], end = row_start[node + 1];
    for (; j + 3 < end; j += 4) {
        int s0 = csr_src[j], s1 = csr_src[j + 1], s2 = csr_src[j + 2], s3 = csr_src[j + 3];
        float w0 = dinv[s0], w1 = dinv[s1], w2 = dinv[s2], w3 = dinv[s3];
        short8 v0 = f8[(size_t)s0 * 16 + lane];
        short8 v1 = f8[(size_t)s1 * 16 + lane];
        short8 v2 = f8[(size_t)s2 * 16 + lane];
        short8 v3 = f8[(size_t)s3 * 16 + lane];
#pragma unroll
        for (int i = 0; i < 8; ++i)
            acc[i] += w0 * bf2f((unsigned short)v0[i]) + w1 * bf2f((unsigned short)v1[i])
                    + w2 * bf2f((unsigned short)v2[i]) + w3 * bf2f((unsigned short)v3[i]);
    }
    for (; j < end; ++j) {
        int s = csr_src[j];
        float w = dinv[s];
        short8 v = f8[(size_t)s * 16 + lane];
#pragma unroll
        for (int i = 0; i < 8; ++i) acc[i] += w * bf2f((unsigned short)v[i]);
    }
    short8 o;
#pragma unroll
    for (int i = 0; i < 8; ++i) o[i] = (short)f2bf(acc[i] * wd);
    ((short8*)out)[(size_t)node * 16 + lane] = o;
}

// ---------------- cmT init: zero + self-loop diagonal folded ----------------
// thread handles 4 consecutive (g, s..s+3)
__global__ void k_zero_cself(const int* __restrict__ batch, const float* __restrict__ dinv,
                             float* __restrict__ cmT) {
    int i = blockIdx.x * blockDim.x + threadIdx.x;   // < NG*NNPAD/4
    if (i >= NG * (NNPAD / 4)) return;
    int g  = i / (NNPAD / 4);
    int s4 = (i % (NNPAD / 4)) * 4;
    float4 o = make_float4(0.f, 0.f, 0.f, 0.f);
    if (s4 + 3 < NN) {
        int4  b  = *(const int4*)(batch + s4);
        float4 dv = *(const float4*)(dinv + s4);
        if (b.x == g) o.x = dv.x * dv.x;
        if (b.y == g) o.y = dv.y * dv.y;
        if (b.z == g) o.z = dv.z * dv.z;
        if (b.w == g) o.w = dv.w * dv.w;
    } else if (s4 < NN) {
        float t[4] = {0.f, 0.f, 0.f, 0.f};
        for (int k = 0; k < 4 && s4 + k < NN; ++k) {
            float dv = dinv[s4 + k];
            if (batch[s4 + k] == g) t[k] = dv * dv;
        }
        o.x = t[0]; o.y = t[1]; o.z = t[2]; o.w = t[3];
    }
    ((float4*)cmT)[i] = o;
}

// transposed coefficient matrix: cmT[g][s] += dinv_s*dinv_d over edges s->d, g=batch[d]
__global__ void k_cbuildT(const int* __restrict__ src, const int* __restrict__ dst,
                          const int2* __restrict__ gdv, const float* __restrict__ dinv,
                          float* __restrict__ cmT, int e) {
    int i = blockIdx.x * blockDim.x + threadIdx.x;
    if (i < e) {
        int s = src[i], d = dst[i];
        int2 g = gdv[d];
        atomicAdd(&cmT[(size_t)g.y * NNPAD + s], dinv[s] * __int_as_float(g.x));
    }
}
__global__ void k_cnth(const int* __restrict__ batch, int* __restrict__ cntg, int n) {
    __shared__ int sh[NG];
    int t = threadIdx.x;
    if (t < NG) sh[t] = 0;
    __syncthreads();
    int i = blockIdx.x * 256 + t;
    if (i < n) atomicAdd(&sh[batch[i]], 1);
    __syncthreads();
    if (t < NG && sh[t]) atomicAdd(&cntg[t], sh[t]);
}

// ---------------- fused: h1-chunk MFMA (in LDS) + pre-partial MFMA ----------------
// Block b: s-band [b*512, b*512+512), 8 chunks of 64 nodes.
// Phase A: D[node(64)][j(256)] = relu(agg1c @ w1t^T + b1) -> Hs[j][s] (bf16, packed 8B writes)
// Phase B: acc2[g(64)][j(256)] += cmTb[:, chunk] @ Hs^T   (K = 64 s)
__global__ __launch_bounds__(512) void k_fused(const unsigned short* __restrict__ agg1,
        const unsigned short* __restrict__ w1t, const float* __restrict__ b1,
        const unsigned short* __restrict__ cmTb, float* __restrict__ partial) {
    __shared__ unsigned short Ws[256 * 128];  // 64 KB
    __shared__ unsigned short As[64 * 128];   // 16 KB
    __shared__ unsigned short Hs[256 * 64];   // 32 KB
    __shared__ unsigned short Cs[64 * 64];    // 8 KB

    const int tid = threadIdx.x;
    const int sb = blockIdx.x * 512;

    // stage Ws once (w1t: 256 x 128 bf16, row-swizzled)
#pragma unroll
    for (int i = 0; i < 8; ++i) {
        int c = tid + i * 512;
        int row = c >> 4, seg = c & 15;
        uint4 v = *(const uint4*)(w1t + row * 128 + seg * 8);
        *(uint4*)((char*)Ws + row * 256 + ((seg * 16) ^ ((row & 7) << 4))) = v;
    }

    const int w  = tid >> 6;
    const int l  = tid & 63;
    const int lr = l & 15;
    const int lg = l >> 4;
    const int swz = (lr & 7) << 4;
    const int j0 = w * 32;

    float bb0 = b1[j0 + lr];
    float bb1 = b1[j0 + 16 + lr];

    f32x4 acc2[4][2] = {};   // persistent pre[g][j] accumulator

    for (int c = 0; c < 8; ++c) {
        int s0 = sb + c * 64;
        __syncthreads();   // Ws ready (c=0) / prev phase-B reads done
        // stage As: 64 nodes x 128 (guard node < NN)
#pragma unroll
        for (int i = 0; i < 2; ++i) {
            int cc = tid + i * 512;
            int row = cc >> 4, seg = cc & 15;
            uint4 v = make_uint4(0, 0, 0, 0);
            int node = s0 + row;
            if (node < NN) v = *(const uint4*)(agg1 + (size_t)node * 128 + seg * 8);
            *(uint4*)((char*)As + row * 256 + ((seg * 16) ^ ((row & 7) << 4))) = v;
        }
        // stage Cs: 64 g x 64 s
        {
            int g = tid >> 3, seg = tid & 7;
            uint4 v = *(const uint4*)(cmTb + (size_t)g * NNPAD + s0 + seg * 8);
            *(uint4*)((char*)Cs + g * 128 + ((seg * 16) ^ ((g & 7) << 4))) = v;
        }
        __syncthreads();

        // phase A: wave w computes D[node 0..64][j0..j0+32], K=128
        f32x4 accA[4][2] = {};
#pragma unroll
        for (int ks = 0; ks < 4; ++ks) {
            int kb = ks * 64 + lg * 16;
            short8 a[4];
#pragma unroll
            for (int m = 0; m < 4; ++m)
                a[m] = *(const short8*)((const char*)As + (m * 16 + lr) * 256 + (kb ^ swz));
#pragma unroll
            for (int n = 0; n < 2; ++n) {
                short8 b = *(const short8*)((const char*)Ws + (j0 + n * 16 + lr) * 256 + (kb ^ swz));
#pragma unroll
                for (int m = 0; m < 4; ++m)
                    accA[m][n] = __builtin_amdgcn_mfma_f32_16x16x32_bf16(a[m], b, accA[m][n], 0, 0, 0);
            }
        }
        // epilogue A: relu+bias, pack 4 consecutive nodes (C/D rows) -> 8B LDS write
#pragma unroll
        for (int n = 0; n < 2; ++n) {
            int j = j0 + n * 16 + lr;
            float bbv = n ? bb1 : bb0;
#pragma unroll
            for (int m = 0; m < 4; ++m) {
                float v0 = fmaxf(accA[m][n][0] + bbv, 0.f);
                float v1 = fmaxf(accA[m][n][1] + bbv, 0.f);
                float v2 = fmaxf(accA[m][n][2] + bbv, 0.f);
                float v3 = fmaxf(accA[m][n][3] + bbv, 0.f);
                uint2 p;
                p.x = (unsigned)f2bf(v0) | ((unsigned)f2bf(v1) << 16);
                p.y = (unsigned)f2bf(v2) | ((unsigned)f2bf(v3) << 16);
                *(uint2*)((char*)Hs + j * 128 + (((m * 16 + lg * 4) * 2) ^ swz)) = p;
            }
        }
        __syncthreads();

        // phase B: acc2[g][j] += Cs(64x64s) x Hs(256j x 64s), K=64
#pragma unroll
        for (int ks = 0; ks < 2; ++ks) {
            int kb = ks * 64 + lg * 16;
            short8 a[4];
#pragma unroll
            for (int mg = 0; mg < 4; ++mg)
                a[mg] = *(const short8*)((const char*)Cs + (mg * 16 + lr) * 128 + (kb ^ swz));
#pragma unroll
            for (int n = 0; n < 2; ++n) {
                short8 b = *(const short8*)((const char*)Hs + (j0 + n * 16 + lr) * 128 + (kb ^ swz));
#pragma unroll
                for (int mg = 0; mg < 4; ++mg)
                    acc2[mg][n] = __builtin_amdgcn_mfma_f32_16x16x32_bf16(a[mg], b, acc2[mg][n], 0, 0, 0);
            }
        }
    }

    float* pb = partial + (size_t)blockIdx.x * (NG * DH);
#pragma unroll
    for (int mg = 0; mg < 4; ++mg)
#pragma unroll
        for (int n = 0; n < 2; ++n)
#pragma unroll
            for (int r = 0; r < 4; ++r) {
                int g = mg * 16 + lg * 4 + r;
                int j = j0 + n * 16 + lr;
                pb[g * DH + j] = acc2[mg][n][r];
            }
}

// reduce partials over 196 blocks
__global__ void k_reduce196(const float* __restrict__ partial, float* __restrict__ pre) {
    int idx = blockIdx.x * 256 + threadIdx.x;
    if (idx >= NG * DH) return;
    float s0 = 0.f, s1 = 0.f, s2 = 0.f, s3 = 0.f;
    for (int b = 0; b < 196; b += 4) {
        s0 += partial[(size_t)b * (NG * DH) + idx];
        s1 += partial[(size_t)(b + 1) * (NG * DH) + idx];
        s2 += partial[(size_t)(b + 2) * (NG * DH) + idx];
        s3 += partial[(size_t)(b + 3) * (NG * DH) + idx];
    }
    pre[idx] = (s0 + s1) + (s2 + s3);
}

// out[g][j] = sum_k pre[g][k] * W2[k][j] + cnt[g]*b2[j]
__global__ void k_fgemm(const float* __restrict__ pre, const float* __restrict__ W2,
                        const float* __restrict__ b2, const int* __restrict__ cntg,
                        float* __restrict__ out) {
    int idx = blockIdx.x * 256 + threadIdx.x;
    if (idx >= NG * DO) return;
    int g = idx >> 7, j = idx & 127;
    float acc = (float)cntg[g] * b2[j];
    const float* pr = pre + g * DH;
    for (int k = 0; k < DH; ++k)
        acc = fmaf(pr[k], W2[k * DO + j], acc);
    out[idx] = acc;
}

// ---------------- launch ----------------

extern "C" void kernel_launch(void* const* d_in, const int* in_sizes, int n_in,
                              void* d_out, int out_size, void* d_ws, size_t ws_size,
                              hipStream_t stream) {
    const float* x     = (const float*)d_in[0];
    const int*   ei    = (const int*)d_in[1];
    const int*   batch = (const int*)d_in[2];
    const float* W1    = (const float*)d_in[3];
    const float* b1    = (const float*)d_in[4];
    const float* W2    = (const float*)d_in[5];
    const float* b2    = (const float*)d_in[6];
    float* out = (float*)d_out;

    const int* src = ei;
    const int* dst = ei + NE;

    // workspace layout (phase-overlapped), peak ~98.6 MB
    char* ws = (char*)d_ws;
    float*          dinv    = (float*)(ws + 0);                  // 400 KB
    int*            cnt_in  = (int*)(ws + 524288);               // deg -> cursor
    int*            rowst   = (int*)(ws + 1048576);              // NN+1
    int*            bsum    = (int*)(ws + 1572864);
    int*            cntg    = (int*)(ws + 1576960);
    unsigned short* w1t     = (unsigned short*)(ws + 1577216);   // 64 KB
    int2*           gdv     = (int2*)(ws + 1642752);             // 800 KB
    int*            csr     = (int*)(ws + 2443264);              // 6.4 MB
    unsigned short* xbf     = (unsigned short*)(ws + 8843264);   // 25.6 MB  [phase 1]
    unsigned short* cmTb    = (unsigned short*)(ws + 8843264);   // 12.85 MB [phase 2, after agg16]
    unsigned short* agg1    = (unsigned short*)(ws + 34443264);  // 25.6 MB
    float*          cmT     = (float*)(ws + 60043264);           // 25.69 MB
    float*          partial = (float*)(ws + 85733376);           // 12.85 MB
    float*          pre     = (float*)(ws + 98578432);           // 64 KB

    const int BLK = 256;
    auto cdiv = [](int a, int b) { return (a + b - 1) / b; };
    const int NB = cdiv(NN, 256);   // 391

    // ---- conversions ----
    k_cvt_bf<<<cdiv(NN * 32, BLK), BLK, 0, stream>>>(x, xbf, NN * 32);
    k_wt<<<cdiv(DI * DH, BLK), BLK, 0, stream>>>(W1, w1t, DI, DH);

    // ---- degree + CSR build ----
    k_zero_int<<<cdiv(NN, BLK), BLK, 0, stream>>>(cnt_in, NN);
    k_hist<<<cdiv(NE, BLK), BLK, 0, stream>>>(dst, cnt_in, NE);
    k_scan1<<<NB, 256, 0, stream>>>(cnt_in, rowst, bsum, NN);
    k_scan2<<<1, 512, 0, stream>>>(bsum, NB);
    k_scan3<<<NB, 256, 0, stream>>>(rowst, bsum, cnt_in, dinv, batch, gdv, NN, NE);
    {
        const int NPASS = 4, NPP = (NN + NPASS - 1) / NPASS;
        for (int p = 0; p < NPASS; ++p)
            k_fill_csr<<<cdiv(NE, BLK), BLK, 0, stream>>>(src, dst, cnt_in, csr, NE,
                                                          p * NPP, (p + 1) * NPP);
    }

    // ---- transposed pool-coefficient matrix cmT (64 x NNPAD) + graph counts ----
    k_zero_cself<<<cdiv(NG * NNPAD / 4, BLK), BLK, 0, stream>>>(batch, dinv, cmT);
    k_cbuildT<<<cdiv(NE, BLK), BLK, 0, stream>>>(src, dst, gdv, dinv, cmT, NE);
    k_zero_int<<<1, 64, 0, stream>>>(cntg, NG);
    k_cnth<<<NB, 256, 0, stream>>>(batch, cntg, NN);

    // ---- layer 1: agg1 = A_hat @ x ----
    k_agg16<<<cdiv(NN * 16, BLK), BLK, 0, stream>>>(xbf, csr, rowst, dinv, agg1, NN);

    // cmT -> bf16 (xbf now dead; cmTb overlays it)
    k_cvt_bf<<<cdiv(NG * NNPAD / 4, BLK), BLK, 0, stream>>>(cmT, cmTb, NG * NNPAD / 4);

    // ---- fused: h1 chunks (MFMA, LDS-resident) + pre-partials (MFMA) ----
    k_fused<<<NNPAD / 512, 512, 0, stream>>>(agg1, w1t, b1, cmTb, partial);

    // ---- tail ----
    k_reduce196<<<cdiv(NG * DH, 256), 256, 0, stream>>>(partial, pre);
    k_fgemm<<<cdiv(NG * DO, 256), 256, 0, stream>>>(pre, W2, b2, cntg, out);
}

// Round 11
// 375.094 us; speedup vs baseline: 1.7590x; 1.0668x over previous
//
#include <hip/hip_runtime.h>

#define NN 100000
#define NNPAD 100352   // 196*512
#define NE 1600000
#define NG 64
#define DI 128
#define DH 256
#define DO 128

using short8 = __attribute__((ext_vector_type(8))) short;
using f32x4  = __attribute__((ext_vector_type(4))) float;

__device__ __forceinline__ float bf2f(unsigned short u) {
    return __uint_as_float(((unsigned)u) << 16);
}
__device__ __forceinline__ unsigned short f2bf(float f) {
    unsigned u = __float_as_uint(f);
    unsigned r = (u + 0x7FFFu + ((u >> 16) & 1u)) >> 16;   // RNE
    return (unsigned short)r;
}

// ---------------- prep: x -> bf16, W1 -> w1t (transposed bf16) ----------------
__global__ void k_prep(const float* __restrict__ x, unsigned short* __restrict__ xbf,
                       const float* __restrict__ W1, unsigned short* __restrict__ w1t) {
    int i = blockIdx.x * blockDim.x + threadIdx.x;
    const int NX4 = NN * 32;
    if (i < NX4) {
        float4 v = ((const float4*)x)[i];
        ushort4 o;
        o.x = f2bf(v.x); o.y = f2bf(v.y); o.z = f2bf(v.z); o.w = f2bf(v.w);
        ((ushort4*)xbf)[i] = o;
    } else if (i < NX4 + DI * DH) {
        int t = i - NX4;
        int k = t / DH, n = t % DH;
        w1t[n * DI + k] = f2bf(W1[t]);
    }
}

__global__ void k_hist(const int* __restrict__ dst, int* __restrict__ cnt, int e) {
    int i = blockIdx.x * blockDim.x + threadIdx.x;
    if (i < e) atomicAdd(&cnt[dst[i]], 1);
}

// ---------------- exclusive scan (2-level) ----------------

__global__ void k_scan1(const int* __restrict__ in, int* __restrict__ out,
                        int* __restrict__ bsum, int n) {
    __shared__ int sh[256];
    int t = threadIdx.x;
    int i = blockIdx.x * 256 + t;
    int v = (i < n) ? in[i] : 0;
    sh[t] = v;
    __syncthreads();
    for (int off = 1; off < 256; off <<= 1) {
        int add = (t >= off) ? sh[t - off] : 0;
        __syncthreads();
        sh[t] += add;
        __syncthreads();
    }
    if (i < n) out[i] = sh[t] - v;
    if (t == 255) bsum[blockIdx.x] = sh[255];
}
__global__ void k_scan2(int* __restrict__ bsum, int* __restrict__ cntg, int nb) {
    __shared__ int sh[512];
    int t = threadIdx.x;
    if (t < NG) cntg[t] = 0;
    int v = (t < nb) ? bsum[t] : 0;
    sh[t] = v;
    __syncthreads();
    for (int off = 1; off < 512; off <<= 1) {
        int add = (t >= off) ? sh[t - off] : 0;
        __syncthreads();
        sh[t] += add;
        __syncthreads();
    }
    if (t < nb) bsum[t] = sh[t] - v;
}
// finalize rowst/cursor, dinv, gdv, cmT self-diagonal (plain store), per-graph counts
__global__ void k_scan3(int* __restrict__ rowst, const int* __restrict__ bsum,
                        int* __restrict__ cursor_deg, float* __restrict__ dinv,
                        const int* __restrict__ batch, int2* __restrict__ gdv,
                        float* __restrict__ cmT, int* __restrict__ cntg,
                        int n, int total) {
    __shared__ int sh[NG];
    int t = threadIdx.x;
    if (t < NG) sh[t] = 0;
    __syncthreads();
    int i = blockIdx.x * 256 + t;
    if (i < n) {
        int deg = cursor_deg[i];
        float dv = rsqrtf((float)(deg + 1));
        dinv[i] = dv;
        int b = batch[i];
        int2 g; g.x = __float_as_int(dv); g.y = b;
        gdv[i] = g;
        cmT[(size_t)b * NNPAD + i] = dv * dv;   // unique slot, cmT pre-zeroed
        atomicAdd(&sh[b], 1);
        int rv = rowst[i] + bsum[blockIdx.x];
        rowst[i] = rv;
        cursor_deg[i] = rv;   // becomes fill cursor
    }
    if (i == 0) rowst[n] = total;
    __syncthreads();
    if (t < NG && sh[t]) atomicAdd(&cntg[t], sh[t]);
}

// ---------------- CSR fill pass 0 + cmT edge accumulation (all edges) ----------------
__global__ void k_fill0(const int* __restrict__ src, const int* __restrict__ dst,
                        const int2* __restrict__ gdv, const float* __restrict__ dinv,
                        int* __restrict__ cursor, int* __restrict__ csr_src,
                        float* __restrict__ cmT, int e, int hi) {
    int i = blockIdx.x * blockDim.x + threadIdx.x;
    if (i < e) {
        int s = src[i], d = dst[i];
        int2 g = gdv[d];
        atomicAdd(&cmT[(size_t)g.y * NNPAD + s], dinv[s] * __int_as_float(g.x));
        if (d < hi) {
            int pos = atomicAdd(&cursor[d], 1);
            csr_src[pos] = s;
        }
    }
}

// CSR fill: remaining dst-range passes
__global__ void k_fill_csr(const int* __restrict__ src, const int* __restrict__ dst,
                           int* __restrict__ cursor, int* __restrict__ csr_src,
                           int e, int lo, int hi) {
    int i = blockIdx.x * blockDim.x + threadIdx.x;
    if (i < e) {
        int d = dst[i];
        if (d >= lo && d < hi) {
            int pos = atomicAdd(&cursor[d], 1);
            csr_src[pos] = src[i];
        }
    }
}

// ---------------- layer-1 aggregation (R5-proven) ----------------
__global__ __launch_bounds__(256) void k_agg16(const unsigned short* __restrict__ feat,
        const int* __restrict__ csr_src, const int* __restrict__ row_start,
        const float* __restrict__ dinv, unsigned short* __restrict__ out, int n) {
    int gid = blockIdx.x * blockDim.x + threadIdx.x;
    int node = gid >> 4;
    int lane = threadIdx.x & 15;
    if (node >= n) return;
    const short8* f8 = (const short8*)feat;
    float wd = dinv[node];
    short8 a = f8[(size_t)node * 16 + lane];
    float acc[8];
#pragma unroll
    for (int i = 0; i < 8; ++i) acc[i] = bf2f((unsigned short)a[i]) * wd;
    int j = row_start[node], end = row_start[node + 1];
    for (; j + 3 < end; j += 4) {
        int s0 = csr_src[j], s1 = csr_src[j + 1], s2 = csr_src[j + 2], s3 = csr_src[j + 3];
        float w0 = dinv[s0], w1 = dinv[s1], w2 = dinv[s2], w3 = dinv[s3];
        short8 v0 = f8[(size_t)s0 * 16 + lane];
        short8 v1 = f8[(size_t)s1 * 16 + lane];
        short8 v2 = f8[(size_t)s2 * 16 + lane];
        short8 v3 = f8[(size_t)s3 * 16 + lane];
#pragma unroll
        for (int i = 0; i < 8; ++i)
            acc[i] += w0 * bf2f((unsigned short)v0[i]) + w1 * bf2f((unsigned short)v1[i])
                    + w2 * bf2f((unsigned short)v2[i]) + w3 * bf2f((unsigned short)v3[i]);
    }
    for (; j < end; ++j) {
        int s = csr_src[j];
        float w = dinv[s];
        short8 v = f8[(size_t)s * 16 + lane];
#pragma unroll
        for (int i = 0; i < 8; ++i) acc[i] += w * bf2f((unsigned short)v[i]);
    }
    short8 o;
#pragma unroll
    for (int i = 0; i < 8; ++i) o[i] = (short)f2bf(acc[i] * wd);
    ((short8*)out)[(size_t)node * 16 + lane] = o;
}

// ---------------- fused: h1-chunk MFMA (LDS) + pre-partial MFMA; Cs staged from f32 cmT ----------------
__global__ __launch_bounds__(512) void k_fused(const unsigned short* __restrict__ agg1,
        const unsigned short* __restrict__ w1t, const float* __restrict__ b1,
        const float* __restrict__ cmT, float* __restrict__ partial) {
    __shared__ unsigned short Ws[256 * 128];  // 64 KB
    __shared__ unsigned short As[64 * 128];   // 16 KB
    __shared__ unsigned short Hs[256 * 64];   // 32 KB
    __shared__ unsigned short Cs[64 * 64];    // 8 KB

    const int tid = threadIdx.x;
    const int sb = blockIdx.x * 512;

#pragma unroll
    for (int i = 0; i < 8; ++i) {
        int c = tid + i * 512;
        int row = c >> 4, seg = c & 15;
        uint4 v = *(const uint4*)(w1t + row * 128 + seg * 8);
        *(uint4*)((char*)Ws + row * 256 + ((seg * 16) ^ ((row & 7) << 4))) = v;
    }

    const int w  = tid >> 6;
    const int l  = tid & 63;
    const int lr = l & 15;
    const int lg = l >> 4;
    const int swz = (lr & 7) << 4;
    const int j0 = w * 32;

    float bb0 = b1[j0 + lr];
    float bb1 = b1[j0 + 16 + lr];

    f32x4 acc2[4][2] = {};

    for (int c = 0; c < 8; ++c) {
        int s0 = sb + c * 64;
        __syncthreads();
        // stage As: 64 nodes x 128
#pragma unroll
        for (int i = 0; i < 2; ++i) {
            int cc = tid + i * 512;
            int row = cc >> 4, seg = cc & 15;
            uint4 v = make_uint4(0, 0, 0, 0);
            int node = s0 + row;
            if (node < NN) v = *(const uint4*)(agg1 + (size_t)node * 128 + seg * 8);
            *(uint4*)((char*)As + row * 256 + ((seg * 16) ^ ((row & 7) << 4))) = v;
        }
        // stage Cs: 64 g x 64 s, f32 -> bf16 inline
        {
            int g = tid >> 3, seg = tid & 7;
            const float* cp = cmT + (size_t)g * NNPAD + s0 + seg * 8;
            float4 f0 = *(const float4*)cp;
            float4 f1 = *(const float4*)(cp + 4);
            uint4 v;
            v.x = (unsigned)f2bf(f0.x) | ((unsigned)f2bf(f0.y) << 16);
            v.y = (unsigned)f2bf(f0.z) | ((unsigned)f2bf(f0.w) << 16);
            v.z = (unsigned)f2bf(f1.x) | ((unsigned)f2bf(f1.y) << 16);
            v.w = (unsigned)f2bf(f1.z) | ((unsigned)f2bf(f1.w) << 16);
            *(uint4*)((char*)Cs + g * 128 + ((seg * 16) ^ ((g & 7) << 4))) = v;
        }
        __syncthreads();

        // phase A: h1 chunk = relu(agg1c @ w1t^T + b1), K=128
        f32x4 accA[4][2] = {};
#pragma unroll
        for (int ks = 0; ks < 4; ++ks) {
            int kb = ks * 64 + lg * 16;
            short8 a[4];
#pragma unroll
            for (int m = 0; m < 4; ++m)
                a[m] = *(const short8*)((const char*)As + (m * 16 + lr) * 256 + (kb ^ swz));
#pragma unroll
            for (int n = 0; n < 2; ++n) {
                short8 b = *(const short8*)((const char*)Ws + (j0 + n * 16 + lr) * 256 + (kb ^ swz));
#pragma unroll
                for (int m = 0; m < 4; ++m)
                    accA[m][n] = __builtin_amdgcn_mfma_f32_16x16x32_bf16(a[m], b, accA[m][n], 0, 0, 0);
            }
        }
#pragma unroll
        for (int n = 0; n < 2; ++n) {
            int j = j0 + n * 16 + lr;
            float bbv = n ? bb1 : bb0;
#pragma unroll
            for (int m = 0; m < 4; ++m) {
                float v0 = fmaxf(accA[m][n][0] + bbv, 0.f);
                float v1 = fmaxf(accA[m][n][1] + bbv, 0.f);
                float v2 = fmaxf(accA[m][n][2] + bbv, 0.f);
                float v3 = fmaxf(accA[m][n][3] + bbv, 0.f);
                uint2 p;
                p.x = (unsigned)f2bf(v0) | ((unsigned)f2bf(v1) << 16);
                p.y = (unsigned)f2bf(v2) | ((unsigned)f2bf(v3) << 16);
                *(uint2*)((char*)Hs + j * 128 + (((m * 16 + lg * 4) * 2) ^ swz)) = p;
            }
        }
        __syncthreads();

        // phase B: acc2[g][j] += Cs @ Hs^T, K=64
#pragma unroll
        for (int ks = 0; ks < 2; ++ks) {
            int kb = ks * 64 + lg * 16;
            short8 a[4];
#pragma unroll
            for (int mg = 0; mg < 4; ++mg)
                a[mg] = *(const short8*)((const char*)Cs + (mg * 16 + lr) * 128 + (kb ^ swz));
#pragma unroll
            for (int n = 0; n < 2; ++n) {
                short8 b = *(const short8*)((const char*)Hs + (j0 + n * 16 + lr) * 128 + (kb ^ swz));
#pragma unroll
                for (int mg = 0; mg < 4; ++mg)
                    acc2[mg][n] = __builtin_amdgcn_mfma_f32_16x16x32_bf16(a[mg], b, acc2[mg][n], 0, 0, 0);
            }
        }
    }

    float* pb = partial + (size_t)blockIdx.x * (NG * DH);
#pragma unroll
    for (int mg = 0; mg < 4; ++mg)
#pragma unroll
        for (int n = 0; n < 2; ++n)
#pragma unroll
            for (int r = 0; r < 4; ++r) {
                int g = mg * 16 + lg * 4 + r;
                int j = j0 + n * 16 + lr;
                pb[g * DH + j] = acc2[mg][n][r];
            }
}

// ---------------- tail: reduce 196 partials + final 64x256x128 GEMM ----------------
__global__ __launch_bounds__(256) void k_tail(const float* __restrict__ partial,
        const float* __restrict__ W2, const float* __restrict__ b2,
        const int* __restrict__ cntg, float* __restrict__ out) {
    __shared__ float pre[DH];
    int g = blockIdx.x;
    int t = threadIdx.x;
    float s0 = 0.f, s1 = 0.f, s2 = 0.f, s3 = 0.f;
    for (int b = 0; b < 196; b += 4) {
        s0 += partial[(size_t)b * (NG * DH) + g * DH + t];
        s1 += partial[(size_t)(b + 1) * (NG * DH) + g * DH + t];
        s2 += partial[(size_t)(b + 2) * (NG * DH) + g * DH + t];
        s3 += partial[(size_t)(b + 3) * (NG * DH) + g * DH + t];
    }
    pre[t] = (s0 + s1) + (s2 + s3);
    __syncthreads();
    if (t < DO) {
        float acc = (float)cntg[g] * b2[t];
        for (int k = 0; k < DH; ++k)
            acc = fmaf(pre[k], W2[k * DO + t], acc);
        out[g * DO + t] = acc;
    }
}

// ---------------- launch ----------------

extern "C" void kernel_launch(void* const* d_in, const int* in_sizes, int n_in,
                              void* d_out, int out_size, void* d_ws, size_t ws_size,
                              hipStream_t stream) {
    const float* x     = (const float*)d_in[0];
    const int*   ei    = (const int*)d_in[1];
    const int*   batch = (const int*)d_in[2];
    const float* W1    = (const float*)d_in[3];
    const float* b1    = (const float*)d_in[4];
    const float* W2    = (const float*)d_in[5];
    const float* b2    = (const float*)d_in[6];
    float* out = (float*)d_out;

    const int* src = ei;
    const int* dst = ei + NE;

    // workspace layout, peak ~98.6 MB
    char* ws = (char*)d_ws;
    float*          dinv    = (float*)(ws + 0);                  // 400 KB
    int*            cnt_in  = (int*)(ws + 524288);               // deg -> cursor
    int*            rowst   = (int*)(ws + 1048576);              // NN+1
    int*            bsum    = (int*)(ws + 1572864);
    int*            cntg    = (int*)(ws + 1576960);
    unsigned short* w1t     = (unsigned short*)(ws + 1577216);   // 64 KB
    int2*           gdv     = (int2*)(ws + 1642752);             // 800 KB
    int*            csr     = (int*)(ws + 2443264);              // 6.4 MB
    unsigned short* xbf     = (unsigned short*)(ws + 8843264);   // 25.6 MB
    unsigned short* agg1    = (unsigned short*)(ws + 34443264);  // 25.6 MB
    float*          cmT     = (float*)(ws + 60043264);           // 25.69 MB
    float*          partial = (float*)(ws + 85733376);           // 12.85 MB

    const int BLK = 256;
    auto cdiv = [](int a, int b) { return (a + b - 1) / b; };
    const int NB = cdiv(NN, 256);   // 391

    // ---- async zero-init ----
    hipMemsetAsync(cmT, 0, (size_t)NG * NNPAD * 4, stream);
    hipMemsetAsync(cnt_in, 0, (size_t)NN * 4, stream);

    // ---- conversions ----
    k_prep<<<cdiv(NN * 32 + DI * DH, BLK), BLK, 0, stream>>>(x, xbf, W1, w1t);

    // ---- degree + scan (+ dinv/gdv/diagonal/graph-counts) ----
    k_hist<<<cdiv(NE, BLK), BLK, 0, stream>>>(dst, cnt_in, NE);
    k_scan1<<<NB, 256, 0, stream>>>(cnt_in, rowst, bsum, NN);
    k_scan2<<<1, 512, 0, stream>>>(bsum, cntg, NB);
    k_scan3<<<NB, 256, 0, stream>>>(rowst, bsum, cnt_in, dinv, batch, gdv, cmT, cntg, NN, NE);

    // ---- CSR fill (pass 0 carries the cmT edge accumulation) ----
    {
        const int NPASS = 4, NPP = (NN + NPASS - 1) / NPASS;
        k_fill0<<<cdiv(NE, BLK), BLK, 0, stream>>>(src, dst, gdv, dinv, cnt_in, csr, cmT, NE, NPP);
        for (int p = 1; p < NPASS; ++p)
            k_fill_csr<<<cdiv(NE, BLK), BLK, 0, stream>>>(src, dst, cnt_in, csr, NE,
                                                          p * NPP, (p + 1) * NPP);
    }

    // ---- layer 1 aggregation ----
    k_agg16<<<cdiv(NN * 16, BLK), BLK, 0, stream>>>(xbf, csr, rowst, dinv, agg1, NN);

    // ---- fused h1 + pre-partials (MFMA) ----
    k_fused<<<NNPAD / 512, 512, 0, stream>>>(agg1, w1t, b1, cmT, partial);

    // ---- tail ----
    k_tail<<<NG, 256, 0, stream>>>(partial, W2, b2, cntg, out);
}